// Round 5
// baseline (520.228 us; speedup 1.0000x reference)
//
#include <hip/hip_runtime.h>

// ---------------- constants ----------------
#define HEADS 6
#define DIM 192
#define DH 32
#define PW 144            // tokens per window
#define WN 960            // windows
#define MWD 15            // MW
#define NTOK (WN*PW)      // 138240
#define SCALE 0.17677669529663687f
#define LOG2E 1.4426950408889634f
#define SCALE2 (SCALE * LOG2E)

typedef __attribute__((ext_vector_type(8))) short bf16x8;
typedef __attribute__((ext_vector_type(4))) short bf16x4;
typedef __attribute__((ext_vector_type(4))) float f32x4;

#define MFMA16(a,b,c) __builtin_amdgcn_mfma_f32_16x16x32_bf16(a,b,c,0,0,0)

__device__ __forceinline__ unsigned short f2bf(float f) {
    unsigned int u = __builtin_bit_cast(unsigned int, f);
    u += 0x7fffu + ((u >> 16) & 1u);
    return (unsigned short)(u >> 16);
}
__device__ __forceinline__ float bf2f(unsigned short s) {
    unsigned int u = ((unsigned int)s) << 16;
    return __builtin_bit_cast(float, u);
}

// ---------------- P: all prep fused into one launch ----------------
// grid = 12960 (cast) + 31104 (bias) + 960 (maskflag) + 576 (weights) = 45600
// Bodies are byte-identical to the previously verified separate kernels;
// only the blockIdx base changes. Branch is block-uniform.
__global__ __launch_bounds__(256) void prep_all(
        const float* __restrict__ x, const float* __restrict__ mask,
        const float* __restrict__ wqkv, const float* __restrict__ wproj,
        const float* __restrict__ btab,
        unsigned short* __restrict__ xb, unsigned short* __restrict__ bias_d,
        unsigned short* __restrict__ wqkvT, unsigned short* __restrict__ wprojT,
        int* __restrict__ flags) {
    __shared__ int any;
    int b = blockIdx.x;
    if (b < 12960) {
        // cast x fp32 -> bf16: 3,317,760 chunks of 8
        long long c = (long long)b * 256 + threadIdx.x;
        const float* p = x + c * 8;
        f32x4 v0 = *(const f32x4*)p;
        f32x4 v1 = *(const f32x4*)(p + 4);
        bf16x8 o;
        o[0] = (short)f2bf(v0[0]); o[1] = (short)f2bf(v0[1]);
        o[2] = (short)f2bf(v0[2]); o[3] = (short)f2bf(v0[3]);
        o[4] = (short)f2bf(v1[0]); o[5] = (short)f2bf(v1[1]);
        o[6] = (short)f2bf(v1[2]); o[7] = (short)f2bf(v1[3]);
        *(bf16x8*)(xb + c * 8) = o;
    } else if (b < 44064) {
        // dense bias [wt][h][i][j] bf16, pre-scaled by log2(e): 7,962,624 elems
        int t = (b - 12960) * 256 + threadIdx.x;
        int j = t % 144;
        int i = (t / 144) % 144;
        int h = (t / 20736) % 6;
        int wt = t / 124416;
        int z1 = i / 72, h1 = (i / 12) % 6, w1 = i % 12;
        int z2 = j / 72, h2 = (j / 12) % 6, w2 = j % 12;
        int pos = (z1 + 2 * z2) * 828 + (h1 + 6 * h2) * 23 + (w1 - w2 + 11);
        bias_d[t] = f2bf(btab[pos * 384 + wt * 6 + h] * LOG2E);
    } else if (b < 45024) {
        // per-window mask-nonzero flag
        int w = b - 44064;
        if (threadIdx.x == 0) any = 0;
        __syncthreads();
        const float* mp = mask + w * 20736;
        int nz = 0;
        for (int c = threadIdx.x; c < 5184; c += 256) {
            f32x4 v = *(const f32x4*)(mp + c * 4);
            if (v[0] != 0.f || v[1] != 0.f || v[2] != 0.f || v[3] != 0.f) nz = 1;
        }
        if (nz) atomicOr(&any, 1);
        __syncthreads();
        if (threadIdx.x == 0) flags[w] = any;
    } else {
        // weight transpose + bf16: 147,456 elems
        int t = (b - 45024) * 256 + threadIdx.x;
        if (t < 576 * 192) {
            int n = t / 192, k = t % 192;
            wqkvT[t] = f2bf(wqkv[k * 576 + n]);
        } else {
            int t2 = t - 576 * 192;
            int n = t2 / 192, k = t2 % 192;
            wprojT[t2] = f2bf(wproj[k * 192 + n]);
        }
    }
}

// ---------------- scatter helpers for qkv_attn phase A ----------------
#define STORE_QK(DST, A, M) { \
    int tok_ = wv * 48 + (M) * 16 + quad * 4; \
    DST[(tok_ + 0) * 40 + col] = f2bf((A)[0]); \
    DST[(tok_ + 1) * 40 + col] = f2bf((A)[1]); \
    DST[(tok_ + 2) * 40 + col] = f2bf((A)[2]); \
    DST[(tok_ + 3) * 40 + col] = f2bf((A)[3]); }
#define STORE_V(A, M) { \
    int tok_ = wv * 48 + (M) * 16 + quad * 4; \
    bf16x4 o_; \
    o_[0] = (short)f2bf((A)[0]); o_[1] = (short)f2bf((A)[1]); \
    o_[2] = (short)f2bf((A)[2]); o_[3] = (short)f2bf((A)[3]); \
    *(bf16x4*)&Vt[col * 168 + tok_] = o_; }

// ---------------- K1: fused qkv + attention, one window per block -----------
// grid 960 (swizzled: 120 consecutive windows per XCD -> bias/wt L2 locality),
// block 192 (3 waves). Per head h: phase A computes q,k,v (144x96 GEMM slice)
// with A-frags (xb, register-held per head) x B-frags (wqkvT, L2-hot,
// ping-pong prefetch across the 6 N-tiles), scattered into the SAME LDS
// layouts the verified attention uses (Ql/Kl stride 40, Vt transposed stride
// 168); barrier; attention phase identical to the R4 kernel (Q from LDS =
// round-0-verified read pattern); barrier before next head overwrites LDS.
// q/k/vt never touch HBM (saves ~318 MB round-trip vs split kernels).
// Wave wv owns rows [wv*48, wv*48+48): it computes q/k/v AND attention for
// exactly those rows, so Ql is wave-private; Kl/Vt are cross-wave (barrier).
// Pad cols [144,160) of Pl and [144,168) of Vt zeroed once; phase A only
// writes cols/toks [0,144), so pads stay zero across all 6 heads.
__global__ __launch_bounds__(192, 3) void qkv_attn(
        const unsigned short* __restrict__ xb, const unsigned short* __restrict__ wqkvT,
        const unsigned short* __restrict__ bias_d, const float* __restrict__ mask,
        const int* __restrict__ mflags, unsigned short* __restrict__ Ob) {
    __shared__ unsigned short Ql[144 * 40];
    __shared__ unsigned short Kl[144 * 40];
    __shared__ unsigned short Vt[32 * 168];
    __shared__ unsigned short Pl[3 * 16 * 168];

    int bx = blockIdx.x;
    int win = (bx & 7) * 120 + (bx >> 3);    // 120 consecutive windows per XCD
    int wt = win / MWD;
    int tid = threadIdx.x;
    int lane = tid & 63, wv = tid >> 6;
    int l16 = lane & 15, quad = lane >> 4;

    // zero pads once (phase A never touches them)
    {
        int row = lane >> 2, ch = lane & 3;
        *(bf16x4*)&Pl[wv * 2688 + row * 168 + 144 + ch * 4] = (bf16x4){0, 0, 0, 0};
    }
    if (tid < 96) {
        int row = tid / 3, off = 144 + (tid % 3) * 8;
        *(bf16x8*)&Vt[row * 168 + off] = (bf16x8){0, 0, 0, 0, 0, 0, 0, 0};
    }
    int mflag = mflags[win];
    const float* maskp = mask + win * 20736;
    const f32x4 z = {0.f, 0.f, 0.f, 0.f};
    int pb = wv * 2688;

    const unsigned short* xp = xb + ((long long)win * 144 + wv * 48 + l16) * 192 + quad * 8;
    const unsigned short* wbase = wqkvT + l16 * 192 + quad * 8;

    for (int h = 0; h < 6; ++h) {
        const unsigned short* biasp = bias_d + (wt * 6 + h) * 20736;
        const unsigned short* wh = wbase + h * (32 * 192);

        // ---- phase A: q,k,v for head h ----
        bf16x8 af[3][6];                      // wave's 3 M-tiles, full K; reloaded per head (L2-hot)
        #pragma unroll
        for (int m = 0; m < 3; ++m)
            #pragma unroll
            for (int kc = 0; kc < 6; ++kc)
                af[m][kc] = *(const bf16x8*)(xp + m * (16 * 192) + kc * 32);

        bf16x8 bA[6], bB[6];
        #pragma unroll
        for (int kc = 0; kc < 6; ++kc) bA[kc] = *(const bf16x8*)(wh + kc * 32);

        // nt: 0,1 = q cols 0-15,16-31; 2,3 = k; 4,5 = v.  n-row offset:
        // (nt>>1)*192 + (nt&1)*16  -> {0,16,192,208,384,400}
        #pragma unroll
        for (int nt = 0; nt < 6; ++nt) {
            bf16x8* bc = (nt & 1) ? bB : bA;
            bf16x8* bn = (nt & 1) ? bA : bB;
            if (nt < 5) {
                int nrow = ((nt + 1) >> 1) * 192 + ((nt + 1) & 1) * 16;
                #pragma unroll
                for (int kc = 0; kc < 6; ++kc)
                    bn[kc] = *(const bf16x8*)(wh + nrow * 192 + kc * 32);
            }
            f32x4 a0 = z, a1 = z, a2 = z;
            #pragma unroll
            for (int kc = 0; kc < 6; ++kc) {
                a0 = MFMA16(af[0][kc], bc[kc], a0);
                a1 = MFMA16(af[1][kc], bc[kc], a1);
                a2 = MFMA16(af[2][kc], bc[kc], a2);
            }
            int col = (nt & 1) * 16 + l16;
            if (nt < 2) {
                STORE_QK(Ql, a0, 0) STORE_QK(Ql, a1, 1) STORE_QK(Ql, a2, 2)
            } else if (nt < 4) {
                STORE_QK(Kl, a0, 0) STORE_QK(Kl, a1, 1) STORE_QK(Kl, a2, 2)
            } else {
                STORE_V(a0, 0) STORE_V(a1, 1) STORE_V(a2, 2)
            }
        }
        __syncthreads();                      // Kl/Vt complete before any wave reads

        // ---- attention for head h (R4-verified body; Q from LDS) ----
        #pragma unroll
        for (int rt = 0; rt < 3; ++rt) {
            int i0 = (wv * 3 + rt) * 16;
            int ibase = (i0 + quad * 4) * 144 + l16;
            bf16x8 aq = *(const bf16x8*)&Ql[(i0 + l16) * 40 + quad * 8];
            f32x4 sreg[9];
            #pragma unroll
            for (int ct = 0; ct < 9; ++ct) {
                bf16x8 bk = *(const bf16x8*)&Kl[(ct * 16 + l16) * 40 + quad * 8];
                sreg[ct] = MFMA16(aq, bk, z);
            }
            if (mflag) {
                #pragma unroll
                for (int ct = 0; ct < 9; ++ct) {
                    #pragma unroll
                    for (int r = 0; r < 4; ++r) {
                        int off = ibase + r * 144 + ct * 16;
                        sreg[ct][r] = fmaf(sreg[ct][r], SCALE2,
                                           fmaf(maskp[off], LOG2E, bf2f(biasp[off])));
                    }
                }
            } else {
                #pragma unroll
                for (int ct = 0; ct < 9; ++ct) {
                    #pragma unroll
                    for (int r = 0; r < 4; ++r) {
                        int off = ibase + r * 144 + ct * 16;
                        sreg[ct][r] = fmaf(sreg[ct][r], SCALE2, bf2f(biasp[off]));
                    }
                }
            }
            float inv[4];
            #pragma unroll
            for (int r = 0; r < 4; ++r) {
                float mx = sreg[0][r];
                #pragma unroll
                for (int ct = 1; ct < 9; ++ct) mx = fmaxf(mx, sreg[ct][r]);
                #pragma unroll
                for (int off = 1; off < 16; off <<= 1) mx = fmaxf(mx, __shfl_xor(mx, off, 64));
                float sum = 0.f;
                #pragma unroll
                for (int ct = 0; ct < 9; ++ct) {
                    float e = __builtin_amdgcn_exp2f(sreg[ct][r] - mx);
                    sreg[ct][r] = e; sum += e;
                }
                #pragma unroll
                for (int off = 1; off < 16; off <<= 1) sum += __shfl_xor(sum, off, 64);
                inv[r] = __builtin_amdgcn_rcpf(sum);
            }
            // store unnormalized P (values in (0,1], bf16-safe)
            #pragma unroll
            for (int ct = 0; ct < 9; ++ct) {
                #pragma unroll
                for (int r = 0; r < 4; ++r)
                    Pl[pb + (quad * 4 + r) * 168 + ct * 16 + l16] = f2bf(sreg[ct][r]);
            }
            f32x4 o0 = z, o1 = z;
            #pragma unroll
            for (int kc = 0; kc < 5; ++kc) {
                bf16x8 ap = *(const bf16x8*)&Pl[pb + l16 * 168 + kc * 32 + quad * 8];
                bf16x8 b0 = *(const bf16x8*)&Vt[l16 * 168 + kc * 32 + quad * 8];
                bf16x8 b1 = *(const bf16x8*)&Vt[(16 + l16) * 168 + kc * 32 + quad * 8];
                o0 = MFMA16(ap, b0, o0);
                o1 = MFMA16(ap, b1, o1);
            }
            #pragma unroll
            for (int r = 0; r < 4; ++r) {
                int i = i0 + quad * 4 + r;
                int ob = (win * 144 + i) * 192 + h * 32 + l16;
                Ob[ob] = f2bf(o0[r] * inv[r]);
                Ob[ob + 16] = f2bf(o1[r] * inv[r]);
            }
        }
        __syncthreads();                      // attention reads done before next head's writes
    }
}

// ---------------- K3: out = O @ w_proj + b_proj, B-resident barrier-free -----
// grid 720 (8 XCD x 90): nblk = s%2, mgroup = r8*45 + s/2. Unchanged from R4.
__global__ __launch_bounds__(256) void out_gemm(
        const unsigned short* __restrict__ Ob, const unsigned short* __restrict__ wprojT,
        const float* __restrict__ bproj, float* __restrict__ out) {
    __shared__ unsigned short Bt[96 * 200];
    int bid = blockIdx.x;
    int r8 = bid & 7, s = bid >> 3;          // s < 90
    int nblk = s % 2;
    int mg = r8 * 45 + s / 2;                // 0..359
    int tid = threadIdx.x;
    int lane = tid & 63, wv = tid >> 6;
    int l16 = lane & 15, quad = lane >> 4;

    const unsigned short* wp = wprojT + nblk * (96 * 192);
    #pragma unroll
    for (int it = 0; it < 9; ++it) {
        int c = tid + it * 256;
        int row = c / 24, c8 = (c % 24) * 8;
        *(bf16x8*)&Bt[row * 200 + c8] = *(const bf16x8*)(wp + c * 8);
    }
    __syncthreads();

    const unsigned short* Abase = Ob + ((long long)mg * 6 * 64 + wv * 16 + l16) * 192
                                  + quad * 8;
    bf16x8 a0[6], a1[6];
    #pragma unroll
    for (int kc = 0; kc < 6; ++kc) a0[kc] = *(const bf16x8*)(Abase + kc * 32);

    #pragma unroll
    for (int t = 0; t < 6; ++t) {
        bf16x8* ac = (t & 1) ? a1 : a0;
        bf16x8* an = (t & 1) ? a0 : a1;
        if (t < 5) {
            const unsigned short* Anext = Abase + (long long)(t + 1) * (64 * 192);
            #pragma unroll
            for (int kc = 0; kc < 6; ++kc) an[kc] = *(const bf16x8*)(Anext + kc * 32);
        }
        f32x4 acc[6];
        #pragma unroll
        for (int i = 0; i < 6; ++i) acc[i] = (f32x4){0.f, 0.f, 0.f, 0.f};
        #pragma unroll
        for (int kc = 0; kc < 6; ++kc) {
            bf16x8 af = ac[kc];
            #pragma unroll
            for (int ct = 0; ct < 6; ++ct) {
                bf16x8 bfr = *(const bf16x8*)&Bt[(ct * 16 + l16) * 200 + kc * 32 + quad * 8];
                acc[ct] = MFMA16(af, bfr, acc[ct]);
            }
        }
        int token0 = (mg * 6 + t) * 64 + wv * 16 + quad * 4;
        #pragma unroll
        for (int ct = 0; ct < 6; ++ct) {
            int c = nblk * 96 + ct * 16 + l16;
            float bp = bproj[c];
            #pragma unroll
            for (int r = 0; r < 4; ++r)
                out[(token0 + r) * 192 + c] = acc[ct][r] + bp;
        }
    }
}

// ---------------- launch ----------------
extern "C" void kernel_launch(void* const* d_in, const int* in_sizes, int n_in,
                              void* d_out, int out_size, void* d_ws, size_t ws_size,
                              hipStream_t stream) {
    const float* x     = (const float*)d_in[0];
    const float* mask  = (const float*)d_in[1];
    const float* wqkv  = (const float*)d_in[2];
    const float* wproj = (const float*)d_in[3];
    const float* bproj = (const float*)d_in[4];
    const float* btab  = (const float*)d_in[5];
    float* out = (float*)d_out;
    // mask flags live in the first 3840 B of d_out: written by prep_all,
    // read by qkv_attn, then fully overwritten by out_gemm (stream-ordered).
    int* mflags = (int*)d_out;

    char* ws = (char*)d_ws;
    // ws layout (bytes). xb stays live through qkv_attn, so Ob is separate.
    unsigned short* xb     = (unsigned short*)(ws + 0);            // 53,084,160
    unsigned short* Ob     = (unsigned short*)(ws + 53084160);     // 53,084,160
    unsigned short* bias_d = (unsigned short*)(ws + 106168320);    // 15,925,248
    unsigned short* wqkvT  = (unsigned short*)(ws + 122093568);    //    221,184
    unsigned short* wprojT = (unsigned short*)(ws + 122314752);    //     73,728
    // total: 122,388,480 bytes (< previous 228.5 MB footprint)

    prep_all<<<45600, 256, 0, stream>>>(x, mask, wqkv, wproj, btab,
                                        xb, bias_d, wqkvT, wprojT, mflags);
    qkv_attn<<<960, 192, 0, stream>>>(xb, wqkvT, bias_d, mask, mflags, Ob);
    out_gemm<<<720, 256, 0, stream>>>(Ob, wprojT, bproj, out);
}

// Round 6
// 452.777 us; speedup vs baseline: 1.1490x; 1.1490x over previous
//
#include <hip/hip_runtime.h>

// ---------------- constants ----------------
#define HEADS 6
#define DIM 192
#define DH 32
#define PW 144            // tokens per window
#define WN 960            // windows
#define MWD 15            // MW
#define NTOK (WN*PW)      // 138240
#define SCALE 0.17677669529663687f
#define LOG2E 1.4426950408889634f
#define SCALE2 (SCALE * LOG2E)

typedef __attribute__((ext_vector_type(8))) short bf16x8;
typedef __attribute__((ext_vector_type(4))) short bf16x4;
typedef __attribute__((ext_vector_type(4))) float f32x4;

#define MFMA16(a,b,c) __builtin_amdgcn_mfma_f32_16x16x32_bf16(a,b,c,0,0,0)

__device__ __forceinline__ unsigned short f2bf(float f) {
    unsigned int u = __builtin_bit_cast(unsigned int, f);
    u += 0x7fffu + ((u >> 16) & 1u);
    return (unsigned short)(u >> 16);
}
__device__ __forceinline__ float bf2f(unsigned short s) {
    unsigned int u = ((unsigned int)s) << 16;
    return __builtin_bit_cast(float, u);
}

// ---------------- P: all prep fused into one launch (R5-verified) ------------
// grid = 12960 (cast) + 31104 (bias) + 960 (maskflag) + 576 (weights) = 45600
__global__ __launch_bounds__(256) void prep_all(
        const float* __restrict__ x, const float* __restrict__ mask,
        const float* __restrict__ wqkv, const float* __restrict__ wproj,
        const float* __restrict__ btab,
        unsigned short* __restrict__ xb, unsigned short* __restrict__ bias_d,
        unsigned short* __restrict__ wqkvT, unsigned short* __restrict__ wprojT,
        int* __restrict__ flags) {
    __shared__ int any;
    int b = blockIdx.x;
    if (b < 12960) {
        // cast x fp32 -> bf16: 3,317,760 chunks of 8
        long long c = (long long)b * 256 + threadIdx.x;
        const float* p = x + c * 8;
        f32x4 v0 = *(const f32x4*)p;
        f32x4 v1 = *(const f32x4*)(p + 4);
        bf16x8 o;
        o[0] = (short)f2bf(v0[0]); o[1] = (short)f2bf(v0[1]);
        o[2] = (short)f2bf(v0[2]); o[3] = (short)f2bf(v0[3]);
        o[4] = (short)f2bf(v1[0]); o[5] = (short)f2bf(v1[1]);
        o[6] = (short)f2bf(v1[2]); o[7] = (short)f2bf(v1[3]);
        *(bf16x8*)(xb + c * 8) = o;
    } else if (b < 44064) {
        // dense bias [wt][h][i][j] bf16, pre-scaled by log2(e): 7,962,624 elems
        int t = (b - 12960) * 256 + threadIdx.x;
        int j = t % 144;
        int i = (t / 144) % 144;
        int h = (t / 20736) % 6;
        int wt = t / 124416;
        int z1 = i / 72, h1 = (i / 12) % 6, w1 = i % 12;
        int z2 = j / 72, h2 = (j / 12) % 6, w2 = j % 12;
        int pos = (z1 + 2 * z2) * 828 + (h1 + 6 * h2) * 23 + (w1 - w2 + 11);
        bias_d[t] = f2bf(btab[pos * 384 + wt * 6 + h] * LOG2E);
    } else if (b < 45024) {
        // per-window mask-nonzero flag
        int w = b - 44064;
        if (threadIdx.x == 0) any = 0;
        __syncthreads();
        const float* mp = mask + w * 20736;
        int nz = 0;
        for (int c = threadIdx.x; c < 5184; c += 256) {
            f32x4 v = *(const f32x4*)(mp + c * 4);
            if (v[0] != 0.f || v[1] != 0.f || v[2] != 0.f || v[3] != 0.f) nz = 1;
        }
        if (nz) atomicOr(&any, 1);
        __syncthreads();
        if (threadIdx.x == 0) flags[w] = any;
    } else {
        // weight transpose + bf16: 147,456 elems
        int t = (b - 45024) * 256 + threadIdx.x;
        if (t < 576 * 192) {
            int n = t / 192, k = t % 192;
            wqkvT[t] = f2bf(wqkv[k * 576 + n]);
        } else {
            int t2 = t - 576 * 192;
            int n = t2 / 192, k = t2 % 192;
            wprojT[t2] = f2bf(wproj[k * 192 + n]);
        }
    }
}

// ---------------- K1: qkv = xb @ w_qkv, B-resident barrier-free GEMM ---------
// Unchanged from R4 (82 µs verified). grid 2160 (8 XCD x 270), block 256.
__global__ __launch_bounds__(256) void qkv_gemm(
        const unsigned short* __restrict__ xb, const unsigned short* __restrict__ wqkvT,
        unsigned short* __restrict__ qb, unsigned short* __restrict__ kb,
        unsigned short* __restrict__ vtb) {
    __shared__ unsigned short Bt[96 * 200];
    int bid = blockIdx.x;
    int r8 = bid & 7, s = bid >> 3;          // s < 270
    int nblk = s % 6;                        // 0..5
    int mg = r8 * 45 + s / 6;                // 0..359
    int tid = threadIdx.x;
    int lane = tid & 63, wv = tid >> 6;
    int l16 = lane & 15, quad = lane >> 4;

    const unsigned short* wp = wqkvT + nblk * (96 * 192);
    #pragma unroll
    for (int it = 0; it < 9; ++it) {
        int c = tid + it * 256;
        int row = c / 24, c8 = (c % 24) * 8;
        *(bf16x8*)&Bt[row * 200 + c8] = *(const bf16x8*)(wp + c * 8);
    }
    __syncthreads();                          // only barrier in the kernel

    const unsigned short* Abase = xb + ((long long)mg * 6 * 64 + wv * 16 + l16) * 192
                                  + quad * 8;
    bf16x8 a0[6], a1[6];
    #pragma unroll
    for (int kc = 0; kc < 6; ++kc) a0[kc] = *(const bf16x8*)(Abase + kc * 32);

    #pragma unroll
    for (int t = 0; t < 6; ++t) {
        bf16x8* ac = (t & 1) ? a1 : a0;
        bf16x8* an = (t & 1) ? a0 : a1;
        if (t < 5) {
            const unsigned short* Anext = Abase + (long long)(t + 1) * (64 * 192);
            #pragma unroll
            for (int kc = 0; kc < 6; ++kc) an[kc] = *(const bf16x8*)(Anext + kc * 32);
        }
        f32x4 acc[6];
        #pragma unroll
        for (int i = 0; i < 6; ++i) acc[i] = (f32x4){0.f, 0.f, 0.f, 0.f};
        #pragma unroll
        for (int kc = 0; kc < 6; ++kc) {
            bf16x8 af = ac[kc];
            #pragma unroll
            for (int ct = 0; ct < 6; ++ct) {
                bf16x8 bfr = *(const bf16x8*)&Bt[(ct * 16 + l16) * 200 + kc * 32 + quad * 8];
                acc[ct] = MFMA16(af, bfr, acc[ct]);
            }
        }
        int mtile = mg * 6 + t;
        int token0 = mtile * 64 + wv * 16 + quad * 4;
        int win = token0 / 144;
        int p0 = token0 - win * 144;         // p0..p0+3 stay in-window
        #pragma unroll
        for (int ct = 0; ct < 6; ++ct) {
            int c0 = nblk * 96 + ct * 16;
            int which = c0 / 192;
            int head = (c0 % 192) / 32;
            int d = (c0 % 32) + l16;
            if (which == 0) {
                int base = ((win * 6 + head) * 144 + p0) * 32 + d;
                #pragma unroll
                for (int r = 0; r < 4; ++r) qb[base + r * 32] = f2bf(acc[ct][r]);
            } else if (which == 1) {
                int base = ((win * 6 + head) * 144 + p0) * 32 + d;
                #pragma unroll
                for (int r = 0; r < 4; ++r) kb[base + r * 32] = f2bf(acc[ct][r]);
            } else {
                int base = ((win * 6 + head) * 32 + d) * 144 + p0;   // transposed
                bf16x4 o;
                #pragma unroll
                for (int r = 0; r < 4; ++r) o[r] = (short)f2bf(acc[ct][r]);
                *(bf16x4*)&vtb[base] = o;
            }
        }
    }
}

// ---------------- K2: attention per (window, head) — unchanged from R4 ------
__global__ __launch_bounds__(192, 3) void attn(
        const unsigned short* __restrict__ qb, const unsigned short* __restrict__ kb,
        const unsigned short* __restrict__ vtb, const unsigned short* __restrict__ bias_d,
        const float* __restrict__ mask, const int* __restrict__ mflags,
        unsigned short* __restrict__ Ob) {
    __shared__ unsigned short Kl[144 * 40];
    __shared__ unsigned short Vt[32 * 168];
    __shared__ unsigned short Pl[3 * 16 * 168];

    int bx = blockIdx.x;
    int r8 = bx & 7, s = bx >> 3;            // s < 720
    int h = s % 6;
    int win = r8 * 120 + s / 6;              // all heads of win -> XCD r8
    int wt = win / MWD;
    int tid = threadIdx.x;
    int lane = tid & 63, wv = tid >> 6;
    int l16 = lane & 15, quad = lane >> 4;

    int qoff = (win * 6 + h) * (144 * 32);
    #pragma unroll
    for (int it = 0; it < 3; ++it) {
        int c = tid + it * 192;
        int row = c >> 2, c8 = (c & 3) * 8;
        *(bf16x8*)&Kl[row * 40 + c8] = *(const bf16x8*)(kb + qoff + c * 8);
        int vr = c / 18, vc = (c % 18) * 8;
        *(bf16x8*)&Vt[vr * 168 + vc] = *(const bf16x8*)(vtb + qoff + c * 8);
    }
    bf16x8 qreg[3];
    #pragma unroll
    for (int rt = 0; rt < 3; ++rt)
        qreg[rt] = *(const bf16x8*)(qb + qoff + (((wv * 3 + rt) * 16) + l16) * 32 + quad * 8);
    {
        int row = lane >> 2, ch = lane & 3;
        *(bf16x4*)&Pl[wv * 2688 + row * 168 + 144 + ch * 4] = (bf16x4){0, 0, 0, 0};
    }
    if (tid < 96) {
        int row = tid / 3, off = 144 + (tid % 3) * 8;
        *(bf16x8*)&Vt[row * 168 + off] = (bf16x8){0, 0, 0, 0, 0, 0, 0, 0};
    }
    int mflag = mflags[win];
    __syncthreads();

    const float* maskp = mask + win * 20736;
    const unsigned short* biasp = bias_d + (wt * 6 + h) * 20736;
    const f32x4 z = {0.f, 0.f, 0.f, 0.f};
    int pb = wv * 2688;

    #pragma unroll
    for (int rt = 0; rt < 3; ++rt) {
        int i0 = (wv * 3 + rt) * 16;
        int ibase = (i0 + quad * 4) * 144 + l16;
        f32x4 bm[9];
        if (mflag) {
            #pragma unroll
            for (int ct = 0; ct < 9; ++ct) {
                #pragma unroll
                for (int r = 0; r < 4; ++r) {
                    int off = ibase + r * 144 + ct * 16;
                    bm[ct][r] = fmaf(maskp[off], LOG2E, bf2f(biasp[off]));
                }
            }
        } else {
            #pragma unroll
            for (int ct = 0; ct < 9; ++ct) {
                #pragma unroll
                for (int r = 0; r < 4; ++r) {
                    int off = ibase + r * 144 + ct * 16;
                    bm[ct][r] = bf2f(biasp[off]);
                }
            }
        }
        bf16x8 aq = qreg[rt];
        f32x4 sreg[9];
        #pragma unroll
        for (int ct = 0; ct < 9; ++ct) {
            bf16x8 bk = *(const bf16x8*)&Kl[(ct * 16 + l16) * 40 + quad * 8];
            sreg[ct] = MFMA16(aq, bk, z);
        }
        #pragma unroll
        for (int ct = 0; ct < 9; ++ct) {
            #pragma unroll
            for (int r = 0; r < 4; ++r)
                sreg[ct][r] = fmaf(sreg[ct][r], SCALE2, bm[ct][r]);
        }
        float inv[4];
        #pragma unroll
        for (int r = 0; r < 4; ++r) {
            float mx = sreg[0][r];
            #pragma unroll
            for (int ct = 1; ct < 9; ++ct) mx = fmaxf(mx, sreg[ct][r]);
            #pragma unroll
            for (int off = 1; off < 16; off <<= 1) mx = fmaxf(mx, __shfl_xor(mx, off, 64));
            float sum = 0.f;
            #pragma unroll
            for (int ct = 0; ct < 9; ++ct) {
                float e = __builtin_amdgcn_exp2f(sreg[ct][r] - mx);
                sreg[ct][r] = e; sum += e;
            }
            #pragma unroll
            for (int off = 1; off < 16; off <<= 1) sum += __shfl_xor(sum, off, 64);
            inv[r] = __builtin_amdgcn_rcpf(sum);
        }
        #pragma unroll
        for (int ct = 0; ct < 9; ++ct) {
            #pragma unroll
            for (int r = 0; r < 4; ++r)
                Pl[pb + (quad * 4 + r) * 168 + ct * 16 + l16] = f2bf(sreg[ct][r]);
        }
        f32x4 o0 = z, o1 = z;
        #pragma unroll
        for (int kc = 0; kc < 5; ++kc) {
            bf16x8 ap = *(const bf16x8*)&Pl[pb + l16 * 168 + kc * 32 + quad * 8];
            bf16x8 b0 = *(const bf16x8*)&Vt[l16 * 168 + kc * 32 + quad * 8];
            bf16x8 b1 = *(const bf16x8*)&Vt[(16 + l16) * 168 + kc * 32 + quad * 8];
            o0 = MFMA16(ap, b0, o0);
            o1 = MFMA16(ap, b1, o1);
        }
        #pragma unroll
        for (int r = 0; r < 4; ++r) {
            int i = i0 + quad * 4 + r;
            int ob = (win * 144 + i) * 192 + h * 32 + l16;
            Ob[ob] = f2bf(o0[r] * inv[r]);
            Ob[ob + 16] = f2bf(o1[r] * inv[r]);
        }
    }
}

// ---------------- K3: out = O @ w_proj + b_proj, B-resident barrier-free -----
// Unchanged from R4. grid 720 (8 XCD x 90), block 256.
__global__ __launch_bounds__(256) void out_gemm(
        const unsigned short* __restrict__ Ob, const unsigned short* __restrict__ wprojT,
        const float* __restrict__ bproj, float* __restrict__ out) {
    __shared__ unsigned short Bt[96 * 200];
    int bid = blockIdx.x;
    int r8 = bid & 7, s = bid >> 3;          // s < 90
    int nblk = s % 2;
    int mg = r8 * 45 + s / 2;                // 0..359
    int tid = threadIdx.x;
    int lane = tid & 63, wv = tid >> 6;
    int l16 = lane & 15, quad = lane >> 4;

    const unsigned short* wp = wprojT + nblk * (96 * 192);
    #pragma unroll
    for (int it = 0; it < 9; ++it) {
        int c = tid + it * 256;
        int row = c / 24, c8 = (c % 24) * 8;
        *(bf16x8*)&Bt[row * 200 + c8] = *(const bf16x8*)(wp + c * 8);
    }
    __syncthreads();

    const unsigned short* Abase = Ob + ((long long)mg * 6 * 64 + wv * 16 + l16) * 192
                                  + quad * 8;
    bf16x8 a0[6], a1[6];
    #pragma unroll
    for (int kc = 0; kc < 6; ++kc) a0[kc] = *(const bf16x8*)(Abase + kc * 32);

    #pragma unroll
    for (int t = 0; t < 6; ++t) {
        bf16x8* ac = (t & 1) ? a1 : a0;
        bf16x8* an = (t & 1) ? a0 : a1;
        if (t < 5) {
            const unsigned short* Anext = Abase + (long long)(t + 1) * (64 * 192);
            #pragma unroll
            for (int kc = 0; kc < 6; ++kc) an[kc] = *(const bf16x8*)(Anext + kc * 32);
        }
        f32x4 acc[6];
        #pragma unroll
        for (int i = 0; i < 6; ++i) acc[i] = (f32x4){0.f, 0.f, 0.f, 0.f};
        #pragma unroll
        for (int kc = 0; kc < 6; ++kc) {
            bf16x8 af = ac[kc];
            #pragma unroll
            for (int ct = 0; ct < 6; ++ct) {
                bf16x8 bfr = *(const bf16x8*)&Bt[(ct * 16 + l16) * 200 + kc * 32 + quad * 8];
                acc[ct] = MFMA16(af, bfr, acc[ct]);
            }
        }
        int token0 = (mg * 6 + t) * 64 + wv * 16 + quad * 4;
        #pragma unroll
        for (int ct = 0; ct < 6; ++ct) {
            int c = nblk * 96 + ct * 16 + l16;
            float bp = bproj[c];
            #pragma unroll
            for (int r = 0; r < 4; ++r)
                out[(token0 + r) * 192 + c] = acc[ct][r] + bp;
        }
    }
}

// ---------------- launch ----------------
extern "C" void kernel_launch(void* const* d_in, const int* in_sizes, int n_in,
                              void* d_out, int out_size, void* d_ws, size_t ws_size,
                              hipStream_t stream) {
    const float* x     = (const float*)d_in[0];
    const float* mask  = (const float*)d_in[1];
    const float* wqkv  = (const float*)d_in[2];
    const float* wproj = (const float*)d_in[3];
    const float* bproj = (const float*)d_in[4];
    const float* btab  = (const float*)d_in[5];
    float* out = (float*)d_out;
    // mask flags live in the first 3840 B of d_out: written by prep_all,
    // read by attn, then fully overwritten by out_gemm (stream-ordered).
    int* mflags = (int*)d_out;

    char* ws = (char*)d_ws;
    // ws layout (bytes):
    unsigned short* xb     = (unsigned short*)(ws + 0);            // 53,084,160 (union w/ Ob)
    unsigned short* Ob     = (unsigned short*)(ws + 0);            // xb dead before attn writes Ob
    unsigned short* qb     = (unsigned short*)(ws + 53084160);     // 53,084,160
    unsigned short* kb     = (unsigned short*)(ws + 106168320);    // 53,084,160
    unsigned short* vtb    = (unsigned short*)(ws + 159252480);    // 53,084,160
    unsigned short* bias_d = (unsigned short*)(ws + 212336640);    // 15,925,248
    unsigned short* wqkvT  = (unsigned short*)(ws + 228261888);    //    221,184
    unsigned short* wprojT = (unsigned short*)(ws + 228483072);    //     73,728
    // total: 228,556,800 bytes

    prep_all<<<45600, 256, 0, stream>>>(x, mask, wqkv, wproj, btab,
                                        xb, bias_d, wqkvT, wprojT, mflags);
    qkv_gemm<<<2160, 256, 0, stream>>>(xb, wqkvT, qb, kb, vtb);
    attn<<<5760, 192, 0, stream>>>(qb, kb, vtb, bias_d, mask, mflags, Ob);
    out_gemm<<<720, 256, 0, stream>>>(Ob, wprojT, bproj, out);
}

// Round 7
// 442.985 us; speedup vs baseline: 1.1744x; 1.0221x over previous
//
#include <hip/hip_runtime.h>

// ---------------- constants ----------------
#define HEADS 6
#define DIM 192
#define DH 32
#define PW 144            // tokens per window
#define WN 960            // windows
#define MWD 15            // MW
#define NTOK (WN*PW)      // 138240
#define SCALE 0.17677669529663687f
#define LOG2E 1.4426950408889634f
#define SCALE2 (SCALE * LOG2E)

typedef __attribute__((ext_vector_type(8))) short bf16x8;
typedef __attribute__((ext_vector_type(4))) short bf16x4;
typedef __attribute__((ext_vector_type(4))) float f32x4;

#define MFMA16(a,b,c) __builtin_amdgcn_mfma_f32_16x16x32_bf16(a,b,c,0,0,0)

__device__ __forceinline__ unsigned short f2bf(float f) {
    unsigned int u = __builtin_bit_cast(unsigned int, f);
    u += 0x7fffu + ((u >> 16) & 1u);
    return (unsigned short)(u >> 16);
}
__device__ __forceinline__ float bf2f(unsigned short s) {
    unsigned int u = ((unsigned int)s) << 16;
    return __builtin_bit_cast(float, u);
}

// ---------------- P: all prep fused into one launch ----------------
// grid = 12960 (cast) + 384 (bias, one block per (wt,h)) + 960 (maskflag)
//        + 576 (weights) = 14880.
// v7 bias section: stage the 3312-entry table column for (wt,h) into LDS once
// (scattered gather count 7.96M -> 1.27M), then emit the dense 144x144 tile
// with bf16x8 stores (8x fewer store instructions). Output layout unchanged.
__global__ __launch_bounds__(256) void prep_all(
        const float* __restrict__ x, const float* __restrict__ mask,
        const float* __restrict__ wqkv, const float* __restrict__ wproj,
        const float* __restrict__ btab,
        unsigned short* __restrict__ xb, unsigned short* __restrict__ bias_d,
        unsigned short* __restrict__ wqkvT, unsigned short* __restrict__ wprojT,
        int* __restrict__ flags) {
    __shared__ float shtab[3312];
    __shared__ int any;
    int b = blockIdx.x;
    if (b < 12960) {
        // cast x fp32 -> bf16: 3,317,760 chunks of 8
        long long c = (long long)b * 256 + threadIdx.x;
        const float* p = x + c * 8;
        f32x4 v0 = *(const f32x4*)p;
        f32x4 v1 = *(const f32x4*)(p + 4);
        bf16x8 o;
        o[0] = (short)f2bf(v0[0]); o[1] = (short)f2bf(v0[1]);
        o[2] = (short)f2bf(v0[2]); o[3] = (short)f2bf(v0[3]);
        o[4] = (short)f2bf(v1[0]); o[5] = (short)f2bf(v1[1]);
        o[6] = (short)f2bf(v1[2]); o[7] = (short)f2bf(v1[3]);
        *(bf16x8*)(xb + c * 8) = o;
    } else if (b < 13344) {
        // dense bias [wt][h][i][j] bf16, pre-scaled by log2(e), via LDS-staged
        // table column. One block per (wt,h).
        int b2 = b - 12960;                  // 0..383
        int wt = b2 / 6, h = b2 % 6;
        for (int p = threadIdx.x; p < 3312; p += 256)
            shtab[p] = btab[p * 384 + wt * 6 + h] * LOG2E;
        __syncthreads();
        unsigned short* op = bias_d + (wt * 6 + h) * 20736;
        // 20736 elems = 2592 chunks of 8 (j-runs)
        for (int c = threadIdx.x; c < 2592; c += 256) {
            int i = c / 18, j0 = (c % 18) * 8;
            int z1 = i / 72, h1 = (i / 12) % 6, w1 = i % 12;
            int pbase = z1 * 828 + h1 * 23 + w1 + 11;
            bf16x8 o;
            #pragma unroll
            for (int e = 0; e < 8; ++e) {
                int j = j0 + e;
                int z2 = j / 72, h2 = (j / 12) % 6, w2 = j % 12;
                int pos = pbase + z2 * 1656 + h2 * 138 - w2;
                o[e] = (short)f2bf(shtab[pos]);
            }
            *(bf16x8*)(op + i * 144 + j0) = o;
        }
    } else if (b < 14304) {
        // per-window mask-nonzero flag
        int w = b - 13344;
        if (threadIdx.x == 0) any = 0;
        __syncthreads();
        const float* mp = mask + w * 20736;
        int nz = 0;
        for (int c = threadIdx.x; c < 5184; c += 256) {
            f32x4 v = *(const f32x4*)(mp + c * 4);
            if (v[0] != 0.f || v[1] != 0.f || v[2] != 0.f || v[3] != 0.f) nz = 1;
        }
        if (nz) atomicOr(&any, 1);
        __syncthreads();
        if (threadIdx.x == 0) flags[w] = any;
    } else {
        // weight transpose + bf16: 147,456 elems
        int t = (b - 14304) * 256 + threadIdx.x;
        if (t < 576 * 192) {
            int n = t / 192, k = t % 192;
            wqkvT[t] = f2bf(wqkv[k * 576 + n]);
        } else {
            int t2 = t - 576 * 192;
            int n = t2 / 192, k = t2 % 192;
            wprojT[t2] = f2bf(wproj[k * 192 + n]);
        }
    }
}

// ---------------- K1: qkv = xb @ w_qkv, B-resident barrier-free GEMM ---------
// Unchanged from R4 (82 µs verified). grid 2160 (8 XCD x 270), block 256.
__global__ __launch_bounds__(256) void qkv_gemm(
        const unsigned short* __restrict__ xb, const unsigned short* __restrict__ wqkvT,
        unsigned short* __restrict__ qb, unsigned short* __restrict__ kb,
        unsigned short* __restrict__ vtb) {
    __shared__ unsigned short Bt[96 * 200];
    int bid = blockIdx.x;
    int r8 = bid & 7, s = bid >> 3;          // s < 270
    int nblk = s % 6;                        // 0..5
    int mg = r8 * 45 + s / 6;                // 0..359
    int tid = threadIdx.x;
    int lane = tid & 63, wv = tid >> 6;
    int l16 = lane & 15, quad = lane >> 4;

    const unsigned short* wp = wqkvT + nblk * (96 * 192);
    #pragma unroll
    for (int it = 0; it < 9; ++it) {
        int c = tid + it * 256;
        int row = c / 24, c8 = (c % 24) * 8;
        *(bf16x8*)&Bt[row * 200 + c8] = *(const bf16x8*)(wp + c * 8);
    }
    __syncthreads();                          // only barrier in the kernel

    const unsigned short* Abase = xb + ((long long)mg * 6 * 64 + wv * 16 + l16) * 192
                                  + quad * 8;
    bf16x8 a0[6], a1[6];
    #pragma unroll
    for (int kc = 0; kc < 6; ++kc) a0[kc] = *(const bf16x8*)(Abase + kc * 32);

    #pragma unroll
    for (int t = 0; t < 6; ++t) {
        bf16x8* ac = (t & 1) ? a1 : a0;
        bf16x8* an = (t & 1) ? a0 : a1;
        if (t < 5) {
            const unsigned short* Anext = Abase + (long long)(t + 1) * (64 * 192);
            #pragma unroll
            for (int kc = 0; kc < 6; ++kc) an[kc] = *(const bf16x8*)(Anext + kc * 32);
        }
        f32x4 acc[6];
        #pragma unroll
        for (int i = 0; i < 6; ++i) acc[i] = (f32x4){0.f, 0.f, 0.f, 0.f};
        #pragma unroll
        for (int kc = 0; kc < 6; ++kc) {
            bf16x8 af = ac[kc];
            #pragma unroll
            for (int ct = 0; ct < 6; ++ct) {
                bf16x8 bfr = *(const bf16x8*)&Bt[(ct * 16 + l16) * 200 + kc * 32 + quad * 8];
                acc[ct] = MFMA16(af, bfr, acc[ct]);
            }
        }
        int mtile = mg * 6 + t;
        int token0 = mtile * 64 + wv * 16 + quad * 4;
        int win = token0 / 144;
        int p0 = token0 - win * 144;         // p0..p0+3 stay in-window
        #pragma unroll
        for (int ct = 0; ct < 6; ++ct) {
            int c0 = nblk * 96 + ct * 16;
            int which = c0 / 192;
            int head = (c0 % 192) / 32;
            int d = (c0 % 32) + l16;
            if (which == 0) {
                int base = ((win * 6 + head) * 144 + p0) * 32 + d;
                #pragma unroll
                for (int r = 0; r < 4; ++r) qb[base + r * 32] = f2bf(acc[ct][r]);
            } else if (which == 1) {
                int base = ((win * 6 + head) * 144 + p0) * 32 + d;
                #pragma unroll
                for (int r = 0; r < 4; ++r) kb[base + r * 32] = f2bf(acc[ct][r]);
            } else {
                int base = ((win * 6 + head) * 32 + d) * 144 + p0;   // transposed
                bf16x4 o;
                #pragma unroll
                for (int r = 0; r < 4; ++r) o[r] = (short)f2bf(acc[ct][r]);
                *(bf16x4*)&vtb[base] = o;
            }
        }
    }
}

// ---------------- K2: attention per (window, head) — unchanged from R4 ------
__global__ __launch_bounds__(192, 3) void attn(
        const unsigned short* __restrict__ qb, const unsigned short* __restrict__ kb,
        const unsigned short* __restrict__ vtb, const unsigned short* __restrict__ bias_d,
        const float* __restrict__ mask, const int* __restrict__ mflags,
        unsigned short* __restrict__ Ob) {
    __shared__ unsigned short Kl[144 * 40];
    __shared__ unsigned short Vt[32 * 168];
    __shared__ unsigned short Pl[3 * 16 * 168];

    int bx = blockIdx.x;
    int r8 = bx & 7, s = bx >> 3;            // s < 720
    int h = s % 6;
    int win = r8 * 120 + s / 6;              // all heads of win -> XCD r8
    int wt = win / MWD;
    int tid = threadIdx.x;
    int lane = tid & 63, wv = tid >> 6;
    int l16 = lane & 15, quad = lane >> 4;

    int qoff = (win * 6 + h) * (144 * 32);
    #pragma unroll
    for (int it = 0; it < 3; ++it) {
        int c = tid + it * 192;
        int row = c >> 2, c8 = (c & 3) * 8;
        *(bf16x8*)&Kl[row * 40 + c8] = *(const bf16x8*)(kb + qoff + c * 8);
        int vr = c / 18, vc = (c % 18) * 8;
        *(bf16x8*)&Vt[vr * 168 + vc] = *(const bf16x8*)(vtb + qoff + c * 8);
    }
    bf16x8 qreg[3];
    #pragma unroll
    for (int rt = 0; rt < 3; ++rt)
        qreg[rt] = *(const bf16x8*)(qb + qoff + (((wv * 3 + rt) * 16) + l16) * 32 + quad * 8);
    {
        int row = lane >> 2, ch = lane & 3;
        *(bf16x4*)&Pl[wv * 2688 + row * 168 + 144 + ch * 4] = (bf16x4){0, 0, 0, 0};
    }
    if (tid < 96) {
        int row = tid / 3, off = 144 + (tid % 3) * 8;
        *(bf16x8*)&Vt[row * 168 + off] = (bf16x8){0, 0, 0, 0, 0, 0, 0, 0};
    }
    int mflag = mflags[win];
    __syncthreads();

    const float* maskp = mask + win * 20736;
    const unsigned short* biasp = bias_d + (wt * 6 + h) * 20736;
    const f32x4 z = {0.f, 0.f, 0.f, 0.f};
    int pb = wv * 2688;

    #pragma unroll
    for (int rt = 0; rt < 3; ++rt) {
        int i0 = (wv * 3 + rt) * 16;
        int ibase = (i0 + quad * 4) * 144 + l16;
        f32x4 bm[9];
        if (mflag) {
            #pragma unroll
            for (int ct = 0; ct < 9; ++ct) {
                #pragma unroll
                for (int r = 0; r < 4; ++r) {
                    int off = ibase + r * 144 + ct * 16;
                    bm[ct][r] = fmaf(maskp[off], LOG2E, bf2f(biasp[off]));
                }
            }
        } else {
            #pragma unroll
            for (int ct = 0; ct < 9; ++ct) {
                #pragma unroll
                for (int r = 0; r < 4; ++r) {
                    int off = ibase + r * 144 + ct * 16;
                    bm[ct][r] = bf2f(biasp[off]);
                }
            }
        }
        bf16x8 aq = qreg[rt];
        f32x4 sreg[9];
        #pragma unroll
        for (int ct = 0; ct < 9; ++ct) {
            bf16x8 bk = *(const bf16x8*)&Kl[(ct * 16 + l16) * 40 + quad * 8];
            sreg[ct] = MFMA16(aq, bk, z);
        }
        #pragma unroll
        for (int ct = 0; ct < 9; ++ct) {
            #pragma unroll
            for (int r = 0; r < 4; ++r)
                sreg[ct][r] = fmaf(sreg[ct][r], SCALE2, bm[ct][r]);
        }
        float inv[4];
        #pragma unroll
        for (int r = 0; r < 4; ++r) {
            float mx = sreg[0][r];
            #pragma unroll
            for (int ct = 1; ct < 9; ++ct) mx = fmaxf(mx, sreg[ct][r]);
            #pragma unroll
            for (int off = 1; off < 16; off <<= 1) mx = fmaxf(mx, __shfl_xor(mx, off, 64));
            float sum = 0.f;
            #pragma unroll
            for (int ct = 0; ct < 9; ++ct) {
                float e = __builtin_amdgcn_exp2f(sreg[ct][r] - mx);
                sreg[ct][r] = e; sum += e;
            }
            #pragma unroll
            for (int off = 1; off < 16; off <<= 1) sum += __shfl_xor(sum, off, 64);
            inv[r] = __builtin_amdgcn_rcpf(sum);
        }
        #pragma unroll
        for (int ct = 0; ct < 9; ++ct) {
            #pragma unroll
            for (int r = 0; r < 4; ++r)
                Pl[pb + (quad * 4 + r) * 168 + ct * 16 + l16] = f2bf(sreg[ct][r]);
        }
        f32x4 o0 = z, o1 = z;
        #pragma unroll
        for (int kc = 0; kc < 5; ++kc) {
            bf16x8 ap = *(const bf16x8*)&Pl[pb + l16 * 168 + kc * 32 + quad * 8];
            bf16x8 b0 = *(const bf16x8*)&Vt[l16 * 168 + kc * 32 + quad * 8];
            bf16x8 b1 = *(const bf16x8*)&Vt[(16 + l16) * 168 + kc * 32 + quad * 8];
            o0 = MFMA16(ap, b0, o0);
            o1 = MFMA16(ap, b1, o1);
        }
        #pragma unroll
        for (int r = 0; r < 4; ++r) {
            int i = i0 + quad * 4 + r;
            int ob = (win * 144 + i) * 192 + h * 32 + l16;
            Ob[ob] = f2bf(o0[r] * inv[r]);
            Ob[ob + 16] = f2bf(o1[r] * inv[r]);
        }
    }
}

// ---------------- K3: out = O @ w_proj + b_proj, B-resident barrier-free -----
// Unchanged from R4. grid 720 (8 XCD x 90), block 256.
__global__ __launch_bounds__(256) void out_gemm(
        const unsigned short* __restrict__ Ob, const unsigned short* __restrict__ wprojT,
        const float* __restrict__ bproj, float* __restrict__ out) {
    __shared__ unsigned short Bt[96 * 200];
    int bid = blockIdx.x;
    int r8 = bid & 7, s = bid >> 3;          // s < 90
    int nblk = s % 2;
    int mg = r8 * 45 + s / 2;                // 0..359
    int tid = threadIdx.x;
    int lane = tid & 63, wv = tid >> 6;
    int l16 = lane & 15, quad = lane >> 4;

    const unsigned short* wp = wprojT + nblk * (96 * 192);
    #pragma unroll
    for (int it = 0; it < 9; ++it) {
        int c = tid + it * 256;
        int row = c / 24, c8 = (c % 24) * 8;
        *(bf16x8*)&Bt[row * 200 + c8] = *(const bf16x8*)(wp + c * 8);
    }
    __syncthreads();

    const unsigned short* Abase = Ob + ((long long)mg * 6 * 64 + wv * 16 + l16) * 192
                                  + quad * 8;
    bf16x8 a0[6], a1[6];
    #pragma unroll
    for (int kc = 0; kc < 6; ++kc) a0[kc] = *(const bf16x8*)(Abase + kc * 32);

    #pragma unroll
    for (int t = 0; t < 6; ++t) {
        bf16x8* ac = (t & 1) ? a1 : a0;
        bf16x8* an = (t & 1) ? a0 : a1;
        if (t < 5) {
            const unsigned short* Anext = Abase + (long long)(t + 1) * (64 * 192);
            #pragma unroll
            for (int kc = 0; kc < 6; ++kc) an[kc] = *(const bf16x8*)(Anext + kc * 32);
        }
        f32x4 acc[6];
        #pragma unroll
        for (int i = 0; i < 6; ++i) acc[i] = (f32x4){0.f, 0.f, 0.f, 0.f};
        #pragma unroll
        for (int kc = 0; kc < 6; ++kc) {
            bf16x8 af = ac[kc];
            #pragma unroll
            for (int ct = 0; ct < 6; ++ct) {
                bf16x8 bfr = *(const bf16x8*)&Bt[(ct * 16 + l16) * 200 + kc * 32 + quad * 8];
                acc[ct] = MFMA16(af, bfr, acc[ct]);
            }
        }
        int token0 = (mg * 6 + t) * 64 + wv * 16 + quad * 4;
        #pragma unroll
        for (int ct = 0; ct < 6; ++ct) {
            int c = nblk * 96 + ct * 16 + l16;
            float bp = bproj[c];
            #pragma unroll
            for (int r = 0; r < 4; ++r)
                out[(token0 + r) * 192 + c] = acc[ct][r] + bp;
        }
    }
}

// ---------------- launch ----------------
extern "C" void kernel_launch(void* const* d_in, const int* in_sizes, int n_in,
                              void* d_out, int out_size, void* d_ws, size_t ws_size,
                              hipStream_t stream) {
    const float* x     = (const float*)d_in[0];
    const float* mask  = (const float*)d_in[1];
    const float* wqkv  = (const float*)d_in[2];
    const float* wproj = (const float*)d_in[3];
    const float* bproj = (const float*)d_in[4];
    const float* btab  = (const float*)d_in[5];
    float* out = (float*)d_out;
    // mask flags live in the first 3840 B of d_out: written by prep_all,
    // read by attn, then fully overwritten by out_gemm (stream-ordered).
    int* mflags = (int*)d_out;

    char* ws = (char*)d_ws;
    // ws layout (bytes):
    unsigned short* xb     = (unsigned short*)(ws + 0);            // 53,084,160 (union w/ Ob)
    unsigned short* Ob     = (unsigned short*)(ws + 0);            // xb dead before attn writes Ob
    unsigned short* qb     = (unsigned short*)(ws + 53084160);     // 53,084,160
    unsigned short* kb     = (unsigned short*)(ws + 106168320);    // 53,084,160
    unsigned short* vtb    = (unsigned short*)(ws + 159252480);    // 53,084,160
    unsigned short* bias_d = (unsigned short*)(ws + 212336640);    // 15,925,248
    unsigned short* wqkvT  = (unsigned short*)(ws + 228261888);    //    221,184
    unsigned short* wprojT = (unsigned short*)(ws + 228483072);    //     73,728
    // total: 228,556,800 bytes

    prep_all<<<14880, 256, 0, stream>>>(x, mask, wqkv, wproj, btab,
                                        xb, bias_d, wqkvT, wprojT, mflags);
    qkv_gemm<<<2160, 256, 0, stream>>>(xb, wqkvT, qb, kb, vtb);
    attn<<<5760, 192, 0, stream>>>(qb, kb, vtb, bias_d, mask, mflags, Ob);
    out_gemm<<<720, 256, 0, stream>>>(Ob, wprojT, bproj, out);
}